// Round 2
// baseline (1824.341 us; speedup 1.0000x reference)
//
#include <hip/hip_runtime.h>
#include <hip/hip_bf16.h>
#include <stdint.h>

// DeepSeekV3 MoE: B=4,S=2048,H=2048, I=1408, E=16, K=2  (T=8192 tokens)
#define T_TOK 8192
#define H_DIM 2048
#define I_DIM 1408
#define E_NUM 16
#define NT1 11            // I_DIM/128
#define NT2 16            // H_DIM/128
#define WLTAB 576         // worklist table capacity (8 classes x 72 slots)
#define GX_WL 577         // grid.x for worklist kernels: 8*72+1 (== 1 mod 8)

typedef __hip_bfloat16 bf16;
typedef __bf16 bf16x8 __attribute__((ext_vector_type(8)));
typedef float f32x4 __attribute__((ext_vector_type(4)));

// meta[] int layout
#define M_CNT 0     // counts[16]
#define M_OFF 16    // offsets[17]
#define M_CUR 33    // cursors[16]
#define WL1_E 64
#define WL1_M0 640
#define WL1_MC 1216
#define WL2_E 1792
#define WL2_M0 2368
#define WL2_MC 2944
#define META_INTS 3520

#define GLOAD_LDS16(g, l)                                                          \
  __builtin_amdgcn_global_load_lds(                                               \
      (const __attribute__((address_space(1))) void*)(g),                         \
      (__attribute__((address_space(3))) void*)(l), 16, 0, 0)

// swizzled LDS element offset for [row][64] bf16 tile, 16B chunk cc (0..7)
__device__ __forceinline__ int lds_off(int row, int cc) {
  return row * 64 + ((cc ^ (row & 7)) * 8);
}

// ---------------------------------------------------------------- meta init
__global__ void zero_meta_kernel(int* __restrict__ meta) {
  const int t = threadIdx.x;
  for (int i = t; i < 64; i += 256) meta[i] = 0;
  for (int i = t; i < WLTAB; i += 256) {
    meta[WL1_E + i] = -1;
    meta[WL2_E + i] = -1;
  }
}

// ---------------------------------------------------------------- fp32 -> bf16
__global__ void cvt_kernel(const float* __restrict__ src, bf16* __restrict__ dst, long n) {
  long i = ((long)blockIdx.x * 256 + threadIdx.x) * 4;
  const long stride = (long)gridDim.x * 256 * 4;
  for (; i < n; i += stride) {
    const float4 v = *reinterpret_cast<const float4*>(src + i);
    union { bf16 b[4]; ushort4 u; } o;
    o.b[0] = __float2bfloat16(v.x);
    o.b[1] = __float2bfloat16(v.y);
    o.b[2] = __float2bfloat16(v.z);
    o.b[3] = __float2bfloat16(v.w);
    *reinterpret_cast<ushort4*>(dst + i) = o.u;
  }
}

// ---------------------------------------------------------------- gating (1 wave / token)
__global__ __launch_bounds__(256) void gate_kernel(
    const float* __restrict__ X, const float* __restrict__ GW,
    const float* __restrict__ bias, int* __restrict__ topk_idx,
    float* __restrict__ topk_gate, int* __restrict__ meta) {
  const int lane = threadIdx.x & 63;
  const int t = blockIdx.x * 4 + (threadIdx.x >> 6);
  const float* xr = X + (size_t)t * H_DIM;
  float acc[E_NUM];
#pragma unroll
  for (int e = 0; e < E_NUM; ++e) acc[e] = 0.f;
  for (int h = lane; h < H_DIM; h += 64) {
    const float xv = xr[h];
#pragma unroll
    for (int e = 0; e < E_NUM; ++e) acc[e] += xv * GW[e * H_DIM + h];
  }
#pragma unroll
  for (int o = 32; o > 0; o >>= 1) {
#pragma unroll
    for (int e = 0; e < E_NUM; ++e) acc[e] += __shfl_xor(acc[e], o);
  }
  if (lane == 0) {
    float s[E_NUM], r[E_NUM];
#pragma unroll
    for (int e = 0; e < E_NUM; ++e) {
      s[e] = 1.f / (1.f + expf(-acc[e]));
      r[e] = s[e] + bias[e];
    }
    int i1 = 0;
    for (int e = 1; e < E_NUM; ++e) if (r[e] > r[i1]) i1 = e;
    int i2 = (i1 == 0) ? 1 : 0;
    for (int e = 0; e < E_NUM; ++e) if (e != i1 && r[e] > r[i2]) i2 = e;
    const float g1 = s[i1], g2 = s[i2];
    const float inv = 1.f / (g1 + g2);
    topk_idx[2 * t] = i1;
    topk_idx[2 * t + 1] = i2;
    topk_gate[2 * t] = g1 * inv;
    topk_gate[2 * t + 1] = g2 * inv;
    atomicAdd(&meta[M_CNT + i1], 1);
    atomicAdd(&meta[M_CNT + i2], 1);
  }
}

// ---------------------------------------------------------------- scan: offsets + class-scheduled worklists
__global__ void scan_kernel(int* __restrict__ meta) {
  if (threadIdx.x != 0) return;
  int mt[17];
  int off = 0;
  for (int e = 0; e < E_NUM; ++e) {
    meta[M_OFF + e] = off;
    const int c = meta[M_CNT + e];
    off += c;
    meta[M_CUR + e] = 0;
    mt[e] = (c + 127) >> 7;
  }
  meta[M_OFF + 16] = off;  // == 16384
  mt[16] = T_TOK / 128;    // 64

  // routed experts sorted desc by tile count (LPT greedy)
  int ord[E_NUM];
  for (int i = 0; i < E_NUM; ++i) ord[i] = i;
  for (int i = 1; i < E_NUM; ++i) {
    const int v = ord[i];
    int j = i;
    while (j > 0 && mt[ord[j - 1]] < mt[v]) { ord[j] = ord[j - 1]; --j; }
    ord[j] = v;
  }

  // WL1: routed (atomic per expert) + shared spread as chunks
  {
    int load[8] = {0}, slots[8] = {0};
    for (int i = 0; i < E_NUM; ++i) {
      const int e = ord[i];
      if (mt[e] == 0) continue;
      int r = 0;
      for (int k = 1; k < 8; ++k) if (load[k] < load[r]) r = k;
      for (int c = 0; c < mt[e]; c += 2) {
        const int wx = slots[r] * 8 + r;
        ++slots[r];
        if (wx < WLTAB) {
          meta[WL1_E + wx] = e;
          meta[WL1_M0 + wx] = c;
          meta[WL1_MC + wx] = (mt[e] - c >= 2) ? 2 : 1;
        }
      }
      load[r] += mt[e];
    }
    for (int c = 0; c < 64; c += 2) {
      int r = 0;
      for (int k = 1; k < 8; ++k) if (load[k] < load[r]) r = k;
      const int wx = slots[r] * 8 + r;
      ++slots[r];
      if (wx < WLTAB) {
        meta[WL1_E + wx] = 16;
        meta[WL1_M0 + wx] = c;
        meta[WL1_MC + wx] = 2;
      }
      load[r] += 2;
    }
  }
  // WL2: routed only
  {
    int load[8] = {0}, slots[8] = {0};
    for (int i = 0; i < E_NUM; ++i) {
      const int e = ord[i];
      if (mt[e] == 0) continue;
      int r = 0;
      for (int k = 1; k < 8; ++k) if (load[k] < load[r]) r = k;
      for (int c = 0; c < mt[e]; c += 2) {
        const int wx = slots[r] * 8 + r;
        ++slots[r];
        if (wx < WLTAB) {
          meta[WL2_E + wx] = e;
          meta[WL2_M0 + wx] = c;
          meta[WL2_MC + wx] = (mt[e] - c >= 2) ? 2 : 1;
        }
      }
      load[r] += mt[e];
    }
  }
}

// ---------------------------------------------------------------- scatter tokens into expert lists
__global__ void scatter_kernel(const int* __restrict__ topk_idx,
                               const float* __restrict__ topk_gate,
                               int* __restrict__ meta, int* __restrict__ list_token,
                               float* __restrict__ list_gate) {
  const int t = blockIdx.x * 256 + threadIdx.x;
#pragma unroll
  for (int k = 0; k < 2; ++k) {
    const int e = topk_idx[2 * t + k];
    const float g = topk_gate[2 * t + k];
    const int slot = atomicAdd(&meta[M_CUR + e], 1);
    const int p = meta[M_OFF + e] + slot;
    list_token[p] = t;
    list_gate[p] = g;
  }
}

// ---------------------------------------------------------------- gather routed token rows (bf16, padded)
__global__ void gather_kernel(const bf16* __restrict__ Xb, const int* __restrict__ list_token,
                              bf16* __restrict__ Xg) {
  const int lane = threadIdx.x & 63;
  const int s = blockIdx.x * 4 + (threadIdx.x >> 6);  // slot row, grid covers 16512 rows
  int src = list_token[(s < 2 * T_TOK) ? s : (2 * T_TOK - 1)];
  const ushort4* in = reinterpret_cast<const ushort4*>(Xb + (size_t)src * H_DIM);
  ushort4* outp = reinterpret_cast<ushort4*>(Xg + (size_t)s * H_DIM);
#pragma unroll
  for (int i = 0; i < H_DIM / 4 / 64; ++i) outp[lane + i * 64] = in[lane + i * 64];
}

// ---------------------------------------------------------------- GEMM1 dual: x@W1^T,x@W3^T -> silu*mul*gate
// 128x128 tile, BK=64, 4 waves (2x2), mfma 16x16x32, swizzled LDS, persistent m-chunks.
__global__ __launch_bounds__(256, 2) void gemm1_kernel(
    const bf16* __restrict__ Xg, const bf16* __restrict__ Xs,
    const bf16* __restrict__ W1, const bf16* __restrict__ W3,
    const bf16* __restrict__ SW1, const bf16* __restrict__ SW3,
    bf16* __restrict__ Hout, const int* __restrict__ meta,
    const float* __restrict__ list_gate) {
  __shared__ alignas(16) bf16 As[128 * 64];
  __shared__ alignas(16) bf16 B1s[128 * 64];
  __shared__ alignas(16) bf16 B3s[128 * 64];

  const int wx = blockIdx.x;
  if (wx >= WLTAB) return;
  const int e = meta[WL1_E + wx];
  if (e < 0) return;
  const int m0 = meta[WL1_M0 + wx];
  const int mc = meta[WL1_MC + wx];
  const int nt = blockIdx.y;

  const int tid = threadIdx.x;
  const int lane = tid & 63;
  const int wid = tid >> 6;

  const bf16 *abase, *w1p, *w3p;
  int hbase, nrows, goff;
  if (e == 16) {
    abase = Xs; w1p = SW1; w3p = SW3;
    hbase = 2 * T_TOK; nrows = T_TOK; goff = 0;
  } else {
    goff = meta[M_OFF + e];
    abase = Xg + (size_t)goff * H_DIM;
    w1p = W1 + (size_t)e * I_DIM * H_DIM;
    w3p = W3 + (size_t)e * I_DIM * H_DIM;
    hbase = goff; nrows = meta[M_CNT + e];
  }

  // staging chunks: thread handles c = tid + 256*i (i<4); row=c>>3, swizzled col chunk
  int srow[4];
  size_t aoff[4], boff[4];
#pragma unroll
  for (int i = 0; i < 4; ++i) {
    const int c = tid + 256 * i;
    const int r = c >> 3;
    const int gc = ((c & 7) ^ (r & 7)) * 8;
    srow[i] = r;
    aoff[i] = (size_t)r * H_DIM + gc;
    boff[i] = (size_t)(nt * 128 + r) * H_DIM + gc;
  }

  const int wm = wid >> 1, wn = wid & 1;
  const int fr = lane & 15;
  const int kg = lane >> 4;  // 0..3 -> chunk sub-index

  for (int m = 0; m < mc; ++m) {
    const bf16* am = abase + (size_t)(m0 + m) * 128 * H_DIM;

    f32x4 acc1[4][4], acc3[4][4];
#pragma unroll
    for (int i = 0; i < 4; ++i)
#pragma unroll
      for (int j = 0; j < 4; ++j) {
        acc1[i][j] = (f32x4){0.f, 0.f, 0.f, 0.f};
        acc3[i][j] = (f32x4){0.f, 0.f, 0.f, 0.f};
      }

    for (int kt = 0; kt < H_DIM / 64; ++kt) {
      const int col = kt * 64;
#pragma unroll
      for (int i = 0; i < 4; ++i) {
        bf16* ldst = As + 2048 * i + 512 * wid;
        GLOAD_LDS16(am + aoff[i] + col, ldst);
      }
#pragma unroll
      for (int i = 0; i < 4; ++i) {
        bf16* ldst = B1s + 2048 * i + 512 * wid;
        GLOAD_LDS16(w1p + boff[i] + col, ldst);
      }
#pragma unroll
      for (int i = 0; i < 4; ++i) {
        bf16* ldst = B3s + 2048 * i + 512 * wid;
        GLOAD_LDS16(w3p + boff[i] + col, ldst);
      }
      __syncthreads();

#pragma unroll
      for (int ks = 0; ks < 2; ++ks) {
        bf16x8 a[4], b1[4], b3[4];
        const int cc = 4 * ks + kg;
#pragma unroll
        for (int mf = 0; mf < 4; ++mf)
          a[mf] = *reinterpret_cast<const bf16x8*>(&As[lds_off(wm * 64 + mf * 16 + fr, cc)]);
#pragma unroll
        for (int nf = 0; nf < 4; ++nf) {
          b1[nf] = *reinterpret_cast<const bf16x8*>(&B1s[lds_off(wn * 64 + nf * 16 + fr, cc)]);
          b3[nf] = *reinterpret_cast<const bf16x8*>(&B3s[lds_off(wn * 64 + nf * 16 + fr, cc)]);
        }
#pragma unroll
        for (int mf = 0; mf < 4; ++mf)
#pragma unroll
          for (int nf = 0; nf < 4; ++nf) {
            acc1[mf][nf] = __builtin_amdgcn_mfma_f32_16x16x32_bf16(a[mf], b1[nf], acc1[mf][nf], 0, 0, 0);
            acc3[mf][nf] = __builtin_amdgcn_mfma_f32_16x16x32_bf16(a[mf], b3[nf], acc3[mf][nf], 0, 0, 0);
          }
      }
      __syncthreads();
    }

    // epilogue: C/D map col=lane&15, row=(lane>>4)*4+j
#pragma unroll
    for (int mf = 0; mf < 4; ++mf)
#pragma unroll
      for (int nf = 0; nf < 4; ++nf)
#pragma unroll
        for (int j = 0; j < 4; ++j) {
          const int rl = wm * 64 + mf * 16 + (lane >> 4) * 4 + j;
          const int srel = (m0 + m) * 128 + rl;
          if (srel < nrows) {
            const int col = nt * 128 + wn * 64 + nf * 16 + fr;
            const float z = acc1[mf][nf][j];
            float h = z / (1.f + expf(-z)) * acc3[mf][nf][j];
            if (e != 16) h *= list_gate[goff + srel];
            Hout[(size_t)(hbase + srel) * I_DIM + col] = __float2bfloat16(h);
          }
        }
  }
}

// ---------------------------------------------------------------- GEMM2: h @ W2^T
// SHARED: plain grid (64,16), direct writes. Else: worklist, atomicAdd via token ids.
template <bool SHARED>
__global__ __launch_bounds__(256, 2) void gemm2_kernel(
    const bf16* __restrict__ Hin, const bf16* __restrict__ W2,
    const bf16* __restrict__ SW2, float* __restrict__ Out,
    const int* __restrict__ meta, const int* __restrict__ list_token) {
  __shared__ alignas(16) bf16 As[128 * 64];
  __shared__ alignas(16) bf16 Bs[128 * 64];

  int e = 0, m0, mc, nrows, rowbase;
  const bf16* w2p;
  if constexpr (SHARED) {
    m0 = blockIdx.x; mc = 1;
    nrows = T_TOK; rowbase = 2 * T_TOK;
    w2p = SW2;
  } else {
    const int wx = blockIdx.x;
    if (wx >= WLTAB) return;
    e = meta[WL2_E + wx];
    if (e < 0) return;
    m0 = meta[WL2_M0 + wx];
    mc = meta[WL2_MC + wx];
    rowbase = meta[M_OFF + e];
    nrows = meta[M_CNT + e];
    w2p = W2 + (size_t)e * H_DIM * I_DIM;
  }
  const int nt = blockIdx.y;

  const int tid = threadIdx.x;
  const int lane = tid & 63;
  const int wid = tid >> 6;

  int srow[4];
  size_t aoff[4], boff[4];
#pragma unroll
  for (int i = 0; i < 4; ++i) {
    const int c = tid + 256 * i;
    const int r = c >> 3;
    const int gc = ((c & 7) ^ (r & 7)) * 8;
    srow[i] = r;
    aoff[i] = (size_t)r * I_DIM + gc;
    boff[i] = (size_t)(nt * 128 + r) * I_DIM + gc;
  }

  const int wm = wid >> 1, wn = wid & 1;
  const int fr = lane & 15;
  const int kg = lane >> 4;

  for (int m = 0; m < mc; ++m) {
    const bf16* am = Hin + ((size_t)rowbase + (size_t)(m0 + m) * 128) * I_DIM;

    f32x4 acc[4][4];
#pragma unroll
    for (int i = 0; i < 4; ++i)
#pragma unroll
      for (int j = 0; j < 4; ++j) acc[i][j] = (f32x4){0.f, 0.f, 0.f, 0.f};

    for (int kt = 0; kt < I_DIM / 64; ++kt) {
      const int col = kt * 64;
#pragma unroll
      for (int i = 0; i < 4; ++i) {
        bf16* ldst = As + 2048 * i + 512 * wid;
        GLOAD_LDS16(am + aoff[i] + col, ldst);
      }
#pragma unroll
      for (int i = 0; i < 4; ++i) {
        bf16* ldst = Bs + 2048 * i + 512 * wid;
        GLOAD_LDS16(w2p + boff[i] + col, ldst);
      }
      __syncthreads();

#pragma unroll
      for (int ks = 0; ks < 2; ++ks) {
        bf16x8 a[4], b[4];
        const int cc = 4 * ks + kg;
#pragma unroll
        for (int mf = 0; mf < 4; ++mf)
          a[mf] = *reinterpret_cast<const bf16x8*>(&As[lds_off(wm * 64 + mf * 16 + fr, cc)]);
#pragma unroll
        for (int nf = 0; nf < 4; ++nf)
          b[nf] = *reinterpret_cast<const bf16x8*>(&Bs[lds_off(wn * 64 + nf * 16 + fr, cc)]);
#pragma unroll
        for (int mf = 0; mf < 4; ++mf)
#pragma unroll
          for (int nf = 0; nf < 4; ++nf)
            acc[mf][nf] = __builtin_amdgcn_mfma_f32_16x16x32_bf16(a[mf], b[nf], acc[mf][nf], 0, 0, 0);
      }
      __syncthreads();
    }

#pragma unroll
    for (int mf = 0; mf < 4; ++mf)
#pragma unroll
      for (int nf = 0; nf < 4; ++nf)
#pragma unroll
        for (int j = 0; j < 4; ++j) {
          const int rl = wm * 64 + mf * 16 + (lane >> 4) * 4 + j;
          const int srel = (m0 + m) * 128 + rl;
          const int col = nt * 128 + wn * 64 + nf * 16 + fr;
          const float v = acc[mf][nf][j];
          if constexpr (SHARED) {
            Out[(size_t)srel * H_DIM + col] = v;
          } else {
            if (srel < nrows) {
              const int tok = list_token[rowbase + srel];
              atomicAdd(&Out[(size_t)tok * H_DIM + col], v);
            }
          }
        }
  }
}

// ---------------------------------------------------------------- launch
extern "C" void kernel_launch(void* const* d_in, const int* in_sizes, int n_in,
                              void* d_out, int out_size, void* d_ws, size_t ws_size,
                              hipStream_t stream) {
  const float* x_f = (const float*)d_in[0];
  const float* gw_f = (const float*)d_in[1];
  const float* bias_f = (const float*)d_in[2];
  const float* sw1_f = (const float*)d_in[3];
  const float* sw3_f = (const float*)d_in[4];
  const float* sw2_f = (const float*)d_in[5];
  const float* w1_f = (const float*)d_in[6];
  const float* w3_f = (const float*)d_in[7];
  const float* w2_f = (const float*)d_in[8];
  float* out = (float*)d_out;

  char* ws = (char*)d_ws;
  size_t off = 0;
  auto alloc = [&](size_t bytes) {
    char* p = ws + off;
    off += (bytes + 255) & ~(size_t)255;
    return p;
  };

  bf16* x_bf = (bf16*)alloc((size_t)T_TOK * H_DIM * 2);
  bf16* xg = (bf16*)alloc((size_t)(2 * T_TOK + 128) * H_DIM * 2);
  bf16* sw1_bf = (bf16*)alloc((size_t)I_DIM * H_DIM * 2);
  bf16* sw3_bf = (bf16*)alloc((size_t)I_DIM * H_DIM * 2);
  bf16* sw2_bf = (bf16*)alloc((size_t)H_DIM * I_DIM * 2);
  bf16* w1_bf = (bf16*)alloc((size_t)E_NUM * I_DIM * H_DIM * 2);
  bf16* w3_bf = (bf16*)alloc((size_t)E_NUM * I_DIM * H_DIM * 2);
  bf16* w2_bf = (bf16*)alloc((size_t)E_NUM * H_DIM * I_DIM * 2);
  bf16* h_all = (bf16*)alloc((size_t)(3 * T_TOK + 128) * I_DIM * 2);  // routed 2T + shared T + pad
  int* meta = (int*)alloc(META_INTS * 4);
  int* topk_idx = (int*)alloc((size_t)T_TOK * 2 * 4);
  float* topk_gate = (float*)alloc((size_t)T_TOK * 2 * 4);
  int* list_token = (int*)alloc((size_t)T_TOK * 2 * 4);
  float* list_gate = (float*)alloc((size_t)T_TOK * 2 * 4);

  if (off > ws_size) return;  // diagnosable: output stays poisoned

  zero_meta_kernel<<<1, 256, 0, stream>>>(meta);

  auto cvt = [&](const float* s, bf16* d, long n) {
    int blocks = (int)((n / 4 + 255) / 256);
    if (blocks > 8192) blocks = 8192;
    cvt_kernel<<<blocks, 256, 0, stream>>>(s, d, n);
  };
  cvt(x_f, x_bf, (long)T_TOK * H_DIM);
  cvt(sw1_f, sw1_bf, (long)I_DIM * H_DIM);
  cvt(sw3_f, sw3_bf, (long)I_DIM * H_DIM);
  cvt(sw2_f, sw2_bf, (long)H_DIM * I_DIM);
  cvt(w1_f, w1_bf, (long)E_NUM * I_DIM * H_DIM);
  cvt(w3_f, w3_bf, (long)E_NUM * I_DIM * H_DIM);
  cvt(w2_f, w2_bf, (long)E_NUM * H_DIM * I_DIM);

  gate_kernel<<<T_TOK / 4, 256, 0, stream>>>(x_f, gw_f, bias_f, topk_idx, topk_gate, meta);
  scan_kernel<<<1, 64, 0, stream>>>(meta);
  scatter_kernel<<<T_TOK / 256, 256, 0, stream>>>(topk_idx, topk_gate, meta, list_token, list_gate);
  gather_kernel<<<(2 * T_TOK + 128) / 4, 256, 0, stream>>>(x_bf, list_token, xg);

  // gemm1: unified routed + shared (worklist classes keep same-B blocks on one XCD)
  gemm1_kernel<<<dim3(GX_WL, NT1), 256, 0, stream>>>(
      xg, x_bf, w1_bf, w3_bf, sw1_bf, sw3_bf, h_all, meta, list_gate);

  // gemm2 shared first (direct writes), then routed (atomic accumulate)
  gemm2_kernel<true><<<dim3(T_TOK / 128, NT2), 256, 0, stream>>>(
      h_all, w2_bf, sw2_bf, out, meta, list_token);
  gemm2_kernel<false><<<dim3(GX_WL, NT2), 256, 0, stream>>>(
      h_all, w2_bf, sw2_bf, out, meta, list_token);
}